// Round 2
// baseline (202.242 us; speedup 1.0000x reference)
//
#include <hip/hip_runtime.h>

// VanillaVectorQuantizer: N=131072 positions (B=32,H=64,W=64), D=64, K=512.
// enc layout [B, D, H, W]: element (b,d,p) at b*D*HW + d*HW + p, p=h*64+w.
//
// The harness reference is numpy fp32:
//   dist = fl(fl(sq_x - fl(2*M)) + sq_e), argmin first-index tie-break.
// sq_x ~ 64 dominates -> dist quantized at ulp(64)=7.6e-6 -> ~86 rows have
// EXACT fp32 ties in the top-2 that np.argmin resolves by lowest index.
// We therefore replicate the fp32 rounding chain exactly:
//   - M_k: ascending-d fp32 FMA chain (matches BLAS microkernel accumulation)
//   - sq_x: numpy pairwise_sum(n=64): 8 stride-8 accumulators of pre-rounded
//     squares (mul then add, NO fma), combine ((r0+r1)+(r2+r3))+((r4+r5)+(r6+r7))
//   - sq_e: sequential d-sum of pre-rounded squares (NO fma)
//   - dist: (sq_x - 2*acc) + sq_e, left-assoc, contraction off
//   - strict '<' ascending k == first-index tie-break

#pragma clang fp contract(off)

#define VQ_D 64
#define VQ_K 512
#define VQ_HW 4096
#define VQ_N 131072

__global__ void vq_sqe_kernel(const float* __restrict__ cb,
                              float* __restrict__ sqe) {
    const int k = threadIdx.x;  // 512 threads, one block
    float s = cb[k] * cb[k];    // d = 0 (square rounded, then added: no fma)
    for (int d = 1; d < VQ_D; ++d) {
        const float v = cb[d * VQ_K + k];
        const float sq = v * v;  // contract(off): rounds the square
        s = s + sq;              // then rounds the add (numpy axis-0 reduce)
    }
    sqe[k] = s;
}

__global__ __launch_bounds__(256) void vq_main_kernel(
    const float* __restrict__ enc, const float* __restrict__ cb,
    const float* __restrict__ sqe, float* __restrict__ out) {
    const int t = blockIdx.x * 256 + threadIdx.x;  // position id
    if (t >= VQ_N) return;
    const int b = t >> 12;            // position / (H*W)
    const int r = t & (VQ_HW - 1);    // h*64+w
    const float* xp = enc + (size_t)b * (VQ_D * VQ_HW) + r;

    // Load this position's vector into registers (coalesced across lanes).
    float x[VQ_D];
#pragma unroll
    for (int d = 0; d < VQ_D; ++d) x[d] = xp[(size_t)d * VQ_HW];

    // sq_x: exact emulation of numpy pairwise_sum over fl(x*x), n=64.
    float pr[8];
#pragma unroll
    for (int j = 0; j < 8; ++j) pr[j] = x[j] * x[j];
#pragma unroll
    for (int i = 8; i < VQ_D; i += 8) {
#pragma unroll
        for (int j = 0; j < 8; ++j) {
            const float sq = x[i + j] * x[i + j];  // rounded square
            pr[j] = pr[j] + sq;                    // rounded add
        }
    }
    const float sqx = ((pr[0] + pr[1]) + (pr[2] + pr[3])) +
                      ((pr[4] + pr[5]) + (pr[6] + pr[7]));

    float best = 3.402823466e38f;
    int bestk = 0;

    // K tiled by 16; codebook/sqe indices are wave-uniform -> scalar loads.
    for (int kt = 0; kt < VQ_K; kt += 16) {
        float acc[16];
#pragma unroll
        for (int j = 0; j < 16; ++j) acc[j] = 0.f;
#pragma unroll
        for (int d = 0; d < VQ_D; ++d) {
            const float xd = x[d];
#pragma unroll
            for (int j = 0; j < 16; ++j)  // ascending-d FMA chain == sgemm
                acc[j] = fmaf(xd, cb[d * VQ_K + kt + j], acc[j]);
        }
#pragma unroll
        for (int j = 0; j < 16; ++j) {
            const float m2 = 2.0f * acc[j];     // exact (power of 2)
            const float tmp = sqx - m2;         // rounds: fl(sq_x - 2M)
            const float dist = tmp + sqe[kt + j];  // rounds: + sq_e
            if (dist < best) {  // strict '<': first (lowest) index on ties
                best = dist;
                bestk = kt + j;
            }
        }
    }

    // Gather winning codebook column, store strided (coalesced across lanes).
    float* op = out + (size_t)b * (VQ_D * VQ_HW) + r;
#pragma unroll
    for (int d = 0; d < VQ_D; ++d) op[(size_t)d * VQ_HW] = cb[d * VQ_K + bestk];
}

extern "C" void kernel_launch(void* const* d_in, const int* in_sizes, int n_in,
                              void* d_out, int out_size, void* d_ws, size_t ws_size,
                              hipStream_t stream) {
    const float* enc = (const float*)d_in[0];  // [32,64,64,64]
    const float* cb  = (const float*)d_in[1];  // [64,512]
    float* out = (float*)d_out;
    float* sqe = (float*)d_ws;  // 512 floats

    vq_sqe_kernel<<<1, VQ_K, 0, stream>>>(cb, sqe);
    vq_main_kernel<<<VQ_N / 256, 256, 0, stream>>>(enc, cb, sqe, out);
}